// Round 2
// baseline (2996.965 us; speedup 1.0000x reference)
//
#include <hip/hip_runtime.h>
#include <math.h>

#define N_CTX 4096
#define DIM 512
#define NPERS 16
#define KTOT (NPERS * DIM)   // 8192
#define EPS_NN 0.1f
#define TOPK_K 30

#define BM 128
#define KC 16

// ---------------------------------------------------------------------------
// Kernel 1: invr[p][n] = 0.25 / max(||context[n] * weight[p]||_2, 1e-12)
// (0.25 factor so that invr[p][n]*invr[p][m] carries the 1/P = 1/16 average)
// One wave per (p, n) pair; 4 waves per block -> grid = 65536/4 = 16384.
// ---------------------------------------------------------------------------
__global__ __launch_bounds__(256) void norms_kernel(
    const float* __restrict__ ctx, const float* __restrict__ w,
    float* __restrict__ invr) {
  int wid = threadIdx.x >> 6;
  int lane = threadIdx.x & 63;
  int gid = blockIdx.x * 4 + wid;          // 0 .. 65535
  int p = gid >> 12;                        // 0 .. 15
  int n = gid & (N_CTX - 1);
  const float4* c4 = reinterpret_cast<const float4*>(ctx + (size_t)n * DIM + lane * 8);
  const float4* w4 = reinterpret_cast<const float4*>(w + (size_t)p * DIM + lane * 8);
  float4 c0 = c4[0], c1 = c4[1];
  float4 w0 = w4[0], w1 = w4[1];
  float s = 0.f, v;
  v = c0.x * w0.x; s = fmaf(v, v, s);
  v = c0.y * w0.y; s = fmaf(v, v, s);
  v = c0.z * w0.z; s = fmaf(v, v, s);
  v = c0.w * w0.w; s = fmaf(v, v, s);
  v = c1.x * w1.x; s = fmaf(v, v, s);
  v = c1.y * w1.y; s = fmaf(v, v, s);
  v = c1.z * w1.z; s = fmaf(v, v, s);
  v = c1.w * w1.w; s = fmaf(v, v, s);
#pragma unroll
  for (int off = 32; off; off >>= 1) s += __shfl_down(s, off, 64);
  if (lane == 0) invr[(size_t)p * N_CTX + n] = 0.25f / fmaxf(sqrtf(s), 1e-12f);
}

// ---------------------------------------------------------------------------
// Kernel 2: att = F F^T where F[n, p*512+d] = c[n,d]*w[p,d]*invr[p,n].
// 128x128 tile / block, 256 threads, 8x8 micro-tile per thread.
// Upper-triangle blocks only (by <= bx); mirror-write the transposed tile.
// LDS tiles are k-major so fragments read as float4.
// ---------------------------------------------------------------------------
__global__ __launch_bounds__(256) void att_gemm(
    const float* __restrict__ ctx, const float* __restrict__ w,
    const float* __restrict__ invr, float* __restrict__ out) {
  int bx = blockIdx.x, by = blockIdx.y;
  if (by > bx) return;                      // symmetric: upper triangle only

  __shared__ __align__(16) float As[KC][BM];
  __shared__ __align__(16) float Bs[KC][BM];

  const int t = threadIdx.x;
  const int tx = t & 15, ty = t >> 4;
  const int tx8 = tx * 8, ty8 = ty * 8;
  const int Ro = by * BM, Co = bx * BM;

  const int srow = t >> 1;                  // 0..127 (staged row)
  const int koff = (t & 1) * 8;             // 0 or 8

  float acc[8][8];
#pragma unroll
  for (int i = 0; i < 8; ++i)
#pragma unroll
    for (int j = 0; j < 8; ++j) acc[i][j] = 0.f;

  for (int k0 = 0; k0 < KTOT; k0 += KC) {
    const int p = k0 >> 9;
    const int dbase = (k0 & (DIM - 1)) + koff;

    const float sA = invr[(size_t)p * N_CTX + Ro + srow];
    const float sB = invr[(size_t)p * N_CTX + Co + srow];
    const float4 wv0 = *reinterpret_cast<const float4*>(w + (size_t)p * DIM + dbase);
    const float4 wv1 = *reinterpret_cast<const float4*>(w + (size_t)p * DIM + dbase + 4);
    const float4 av0 = *reinterpret_cast<const float4*>(ctx + (size_t)(Ro + srow) * DIM + dbase);
    const float4 av1 = *reinterpret_cast<const float4*>(ctx + (size_t)(Ro + srow) * DIM + dbase + 4);
    const float4 bv0 = *reinterpret_cast<const float4*>(ctx + (size_t)(Co + srow) * DIM + dbase);
    const float4 bv1 = *reinterpret_cast<const float4*>(ctx + (size_t)(Co + srow) * DIM + dbase + 4);

    __syncthreads();  // previous iteration's reads complete before overwrite

    As[koff + 0][srow] = av0.x * wv0.x * sA;
    As[koff + 1][srow] = av0.y * wv0.y * sA;
    As[koff + 2][srow] = av0.z * wv0.z * sA;
    As[koff + 3][srow] = av0.w * wv0.w * sA;
    As[koff + 4][srow] = av1.x * wv1.x * sA;
    As[koff + 5][srow] = av1.y * wv1.y * sA;
    As[koff + 6][srow] = av1.z * wv1.z * sA;
    As[koff + 7][srow] = av1.w * wv1.w * sA;

    Bs[koff + 0][srow] = bv0.x * wv0.x * sB;
    Bs[koff + 1][srow] = bv0.y * wv0.y * sB;
    Bs[koff + 2][srow] = bv0.z * wv0.z * sB;
    Bs[koff + 3][srow] = bv0.w * wv0.w * sB;
    Bs[koff + 4][srow] = bv1.x * wv1.x * sB;
    Bs[koff + 5][srow] = bv1.y * wv1.y * sB;
    Bs[koff + 6][srow] = bv1.z * wv1.z * sB;
    Bs[koff + 7][srow] = bv1.w * wv1.w * sB;

    __syncthreads();

#pragma unroll
    for (int kk = 0; kk < KC; ++kk) {
      const float4 a0 = *reinterpret_cast<const float4*>(&As[kk][ty8]);
      const float4 a1 = *reinterpret_cast<const float4*>(&As[kk][ty8 + 4]);
      const float4 b0 = *reinterpret_cast<const float4*>(&Bs[kk][tx8]);
      const float4 b1 = *reinterpret_cast<const float4*>(&Bs[kk][tx8 + 4]);
      const float av[8] = {a0.x, a0.y, a0.z, a0.w, a1.x, a1.y, a1.z, a1.w};
      const float bv[8] = {b0.x, b0.y, b0.z, b0.w, b1.x, b1.y, b1.z, b1.w};
#pragma unroll
      for (int i = 0; i < 8; ++i)
#pragma unroll
        for (int j = 0; j < 8; ++j) acc[i][j] = fmaf(av[i], bv[j], acc[i][j]);
    }
  }

  // straight tile
#pragma unroll
  for (int i = 0; i < 8; ++i) {
    size_t base = (size_t)(Ro + ty8 + i) * N_CTX + Co + tx8;
    *reinterpret_cast<float4*>(out + base) =
        make_float4(acc[i][0], acc[i][1], acc[i][2], acc[i][3]);
    *reinterpret_cast<float4*>(out + base + 4) =
        make_float4(acc[i][4], acc[i][5], acc[i][6], acc[i][7]);
  }
  // mirrored tile
  if (bx != by) {
#pragma unroll
    for (int j = 0; j < 8; ++j) {
      size_t base = (size_t)(Co + tx8 + j) * N_CTX + Ro + ty8;
      *reinterpret_cast<float4*>(out + base) =
          make_float4(acc[0][j], acc[1][j], acc[2][j], acc[3][j]);
      *reinterpret_cast<float4*>(out + base + 4) =
          make_float4(acc[4][j], acc[5][j], acc[6][j], acc[7][j]);
    }
  }
}

// ---------------------------------------------------------------------------
// Kernel 3: per-row epsilon threshold + exact top-30 mask (jax.lax.top_k tie
// semantics: ties at the k-th value broken by lowest index). One block/row;
// row lives in registers (16 f32/thread, contiguous chunks). The 30th-largest
// value is found by binary search on float bits (all values >= 0 so the uint
// order matches the float order).
// ---------------------------------------------------------------------------
__global__ __launch_bounds__(256) void topk_kernel(float* __restrict__ att) {
  __shared__ unsigned red[4];
  __shared__ unsigned eqcnt[256];

  const int n = blockIdx.x;
  const int t = threadIdx.x;
  const int wid = t >> 6, lane = t & 63;
  float* row = att + (size_t)n * N_CTX;

  float vr[16];
  unsigned ur[16];
#pragma unroll
  for (int i = 0; i < 4; ++i) {
    float4 v4 = *reinterpret_cast<const float4*>(row + t * 16 + i * 4);
    float tmp[4] = {v4.x, v4.y, v4.z, v4.w};
#pragma unroll
    for (int j = 0; j < 4; ++j) {
      float v = tmp[j];
      v = (v > EPS_NN) ? v : 0.0f;
      vr[i * 4 + j] = v;
      ur[i * 4 + j] = __float_as_uint(v);
    }
  }

  // binary search: smallest u such that count(bits > u) < K  ==>  u = bits(v_k)
  unsigned lo = 0u, hi = 0x7F800000u;
  while (lo < hi) {
    unsigned mid = lo + ((hi - lo) >> 1);
    unsigned c = 0;
#pragma unroll
    for (int i = 0; i < 16; ++i) c += (ur[i] > mid) ? 1u : 0u;
#pragma unroll
    for (int off = 32; off; off >>= 1) c += __shfl_down(c, off, 64);
    if (lane == 0) red[wid] = c;
    __syncthreads();
    unsigned tot = red[0] + red[1] + red[2] + red[3];
    __syncthreads();
    if (tot < TOPK_K) hi = mid; else lo = mid + 1;
  }
  const unsigned kbits = lo;

  // count strictly greater than v_k
  {
    unsigned c = 0;
#pragma unroll
    for (int i = 0; i < 16; ++i) c += (ur[i] > kbits) ? 1u : 0u;
#pragma unroll
    for (int off = 32; off; off >>= 1) c += __shfl_down(c, off, 64);
    if (lane == 0) red[wid] = c;
  }
  __syncthreads();
  const unsigned gt = red[0] + red[1] + red[2] + red[3];
  const unsigned r_eq = TOPK_K - gt;  // how many ==v_k entries to keep (lowest idx)
  __syncthreads();

  // exclusive prefix over per-thread equal-counts (index order = t*16+i)
  unsigned ec = 0;
#pragma unroll
  for (int i = 0; i < 16; ++i) ec += (ur[i] == kbits) ? 1u : 0u;
  eqcnt[t] = ec;
  __syncthreads();
  for (int off = 1; off < 256; off <<= 1) {
    unsigned v = eqcnt[t];
    unsigned add = (t >= off) ? eqcnt[t - off] : 0u;
    __syncthreads();
    eqcnt[t] = v + add;
    __syncthreads();
  }
  const unsigned prefix = eqcnt[t] - ec;

  unsigned seen = 0;
#pragma unroll
  for (int i = 0; i < 16; ++i) {
    float o = 0.0f;
    if (ur[i] > kbits) {
      o = vr[i];
    } else if (kbits != 0u && ur[i] == kbits) {
      if (prefix + seen < r_eq) o = vr[i];
      ++seen;
    }
    vr[i] = o;
  }
#pragma unroll
  for (int i = 0; i < 4; ++i) {
    *reinterpret_cast<float4*>(row + t * 16 + i * 4) =
        make_float4(vr[i * 4], vr[i * 4 + 1], vr[i * 4 + 2], vr[i * 4 + 3]);
  }
}

// ---------------------------------------------------------------------------
extern "C" void kernel_launch(void* const* d_in, const int* in_sizes, int n_in,
                              void* d_out, int out_size, void* d_ws, size_t ws_size,
                              hipStream_t stream) {
  const float* ctx = (const float*)d_in[0];   // (4096, 512)
  const float* w   = (const float*)d_in[1];   // (16, 512)
  float* out = (float*)d_out;                 // (4096, 4096)
  float* invr = (float*)d_ws;                 // 16*4096 f32 = 256 KB scratch

  // 65536 (p,n) pairs, 4 waves (pairs) per block -> 16384 blocks  [R1 bug: /64]
  norms_kernel<<<(NPERS * N_CTX) / 4, 256, 0, stream>>>(ctx, w, invr);

  dim3 grid(N_CTX / BM, N_CTX / BM);          // 32 x 32, lower half early-exits
  att_gemm<<<grid, 256, 0, stream>>>(ctx, w, invr, out);

  topk_kernel<<<N_CTX, 256, 0, stream>>>(out);
}